// Round 8
// baseline (64.363 us; speedup 1.0000x reference)
//
#include <hip/hip_runtime.h>

#define BSZ 512
#define NN  500
#define KK  100
#define SS  96
#define HIDN 32
#define ROWS (BSZ * NN)       // 256000 output rows
#define NF4  (ROWS * SS / 4)  // 6,144,000 float4 elements
#define F4PR (SS / 4)         // 24 float4 per row
#define NSLOT 8
#define FUSE_BLOCKS (NF4 / (256 * NSLOT))  // 3000, exact cover

typedef float vf4 __attribute__((ext_vector_type(4)));

// flag[row]: -1 -> copy x row; -2 -> zero row (gate=0); r>=0 -> kriged row r (gate=1)

// ------- kernel 1: prefix-sum (block 0) + flag clear to -1 (all blocks) -------
__global__ __launch_bounds__(512) void prep_kernel(const int* __restrict__ idx_of_node,
                                                   int* __restrict__ offs,
                                                   int4* __restrict__ flag4) {
    if (blockIdx.x == 0) {
        __shared__ int buf[BSZ];
        int t = threadIdx.x;
        int v = idx_of_node[t];
        buf[t] = v;
        __syncthreads();
        int acc = v;
        for (int d = 1; d < BSZ; d <<= 1) {
            int add = (t >= d) ? buf[t - d] : 0;
            __syncthreads();
            acc += add;
            buf[t] = acc;
            __syncthreads();
        }
        offs[t] = acc - v;  // exclusive prefix
    }
    int n4 = ROWS / 4;  // 64000 int4
    for (int i = blockIdx.x * 512 + threadIdx.x; i < n4; i += gridDim.x * 512)
        flag4[i] = make_int4(-1, -1, -1, -1);
}

// ---------------- kernel 2: gather -> MLP -> gate; write row descriptor ------------
__global__ __launch_bounds__(256) void gate_kernel(
    const float* __restrict__ y, const float* __restrict__ W1,
    const float* __restrict__ b1, const float* __restrict__ W2,
    const float* __restrict__ b2, const float* __restrict__ gumbel,
    const int* __restrict__ krig_idx, const int* __restrict__ offs,
    int* __restrict__ flag) {
    __shared__ float4 w1s[SS * HIDN / 4];  // 12 KB, row-major [s][j]
    __shared__ float b1s[HIDN];
    __shared__ float w2s[HIDN * 2];
    __shared__ float b2s[2];
    for (int i = threadIdx.x; i < SS * HIDN / 4; i += 256)
        w1s[i] = reinterpret_cast<const float4*>(W1)[i];
    if (threadIdx.x < HIDN) b1s[threadIdx.x] = b1[threadIdx.x];
    if (threadIdx.x < 2 * HIDN) w2s[threadIdx.x] = W2[threadIdx.x];
    if (threadIdx.x < 2) b2s[threadIdx.x] = b2[threadIdx.x];
    __syncthreads();

    int r = blockIdx.x * 256 + threadIdx.x;
    if (r >= BSZ * KK) return;
    int b = r / KK;
    int node = krig_idx[r];
    const float4* yrow = reinterpret_cast<const float4*>(y + (size_t)(b * NN + node) * SS);

    float h[HIDN];
#pragma unroll
    for (int j = 0; j < HIDN; ++j) h[j] = b1s[j];
#pragma unroll
    for (int s4 = 0; s4 < F4PR; ++s4) {
        float4 v = yrow[s4];
        float vv[4] = {v.x, v.y, v.z, v.w};
        const float4* wbase = &w1s[s4 * 4 * (HIDN / 4)];
#pragma unroll
        for (int q = 0; q < 4; ++q) {
#pragma unroll
            for (int j4 = 0; j4 < HIDN / 4; ++j4) {
                float4 w = wbase[q * (HIDN / 4) + j4];
                h[j4 * 4 + 0] += vv[q] * w.x;
                h[j4 * 4 + 1] += vv[q] * w.y;
                h[j4 * 4 + 2] += vv[q] * w.z;
                h[j4 * 4 + 3] += vv[q] * w.w;
            }
        }
    }
    float l0 = b2s[0], l1 = b2s[1];
#pragma unroll
    for (int j = 0; j < HIDN; ++j) {
        float hr = fmaxf(h[j], 0.0f);
        l0 += hr * w2s[j * 2 + 0];
        l1 += hr * w2s[j * 2 + 1];
    }
    float g0 = gumbel[r * 2 + 0], g1 = gumbel[r * 2 + 1];
    // straight-through hard gumbel: forward value is exactly one-hot {0,1}
    int on = (l1 + g1 > l0 + g0);
    flag[offs[b] + node] = on ? r : -2;  // gate==0 -> exact zero row
}

// ------- kernel 3: fused single-pass output; per-row tri-state descriptor ----------
__global__ __launch_bounds__(256) void fuse_kernel(
    const vf4* __restrict__ x4, const vf4* __restrict__ y4,
    const vf4* __restrict__ mask4, const int* __restrict__ flag,
    const int* __restrict__ krig_idx, vf4* __restrict__ out4) {
    const int t0 = blockIdx.x * (256 * NSLOT) + threadIdx.x;  // 32 KB contiguous/block

    int fr[NSLOT];
#pragma unroll
    for (int k = 0; k < NSLOT; ++k) {
        int idx = t0 + k * 256;
        fr[k] = flag[idx / F4PR];
    }
    vf4 xv[NSLOT];
#pragma unroll
    for (int k = 0; k < NSLOT; ++k) {
        int idx = t0 + k * 256;
        int r = fr[k];
        vf4 v = (vf4)(0.0f);
        if (r == -1) {
            v = __builtin_nontemporal_load(x4 + idx);  // read-once: don't pollute L3
        } else if (r >= 0) {
            int row = idx / F4PR;
            int c = idx - row * F4PR;
            int b = r / KK;
            int node = krig_idx[r];               // 200 KB table, L2-hit
            vf4 m = mask4[r * F4PR + c];
            v = m * y4[(b * NN + node) * F4PR + c];  // gate==1 folded (exactly 1.0)
        }
        xv[k] = v;                                 // r==-2: exact zeros
    }
#pragma unroll
    for (int k = 0; k < NSLOT; ++k) {
        int idx = t0 + k * 256;
        out4[idx] = xv[k];                          // PLAIN stores this round (A/B vs nt)
    }
}

extern "C" void kernel_launch(void* const* d_in, const int* in_sizes, int n_in,
                              void* d_out, int out_size, void* d_ws, size_t ws_size,
                              hipStream_t stream) {
    const float* x      = (const float*)d_in[0];
    const float* y      = (const float*)d_in[1];
    const float* W1     = (const float*)d_in[2];
    const float* b1     = (const float*)d_in[3];
    const float* W2     = (const float*)d_in[4];
    const float* b2     = (const float*)d_in[5];
    const float* mask   = (const float*)d_in[6];
    const float* gumbel = (const float*)d_in[7];
    const int* krig_idx = (const int*)d_in[8];
    const int* idx_of_node = (const int*)d_in[9];
    float* out = (float*)d_out;

    int* offs = (int*)d_ws;                    // 512 ints
    int* flag = offs + BSZ;                    // 256000 ints (1 MB), 16B-aligned

    prep_kernel<<<128, 512, 0, stream>>>(idx_of_node, offs,
                                         reinterpret_cast<int4*>(flag));

    int rows = BSZ * KK;
    gate_kernel<<<(rows + 255) / 256, 256, 0, stream>>>(
        y, W1, b1, W2, b2, gumbel, krig_idx, offs, flag);

    fuse_kernel<<<FUSE_BLOCKS, 256, 0, stream>>>(
        reinterpret_cast<const vf4*>(x), reinterpret_cast<const vf4*>(y),
        reinterpret_cast<const vf4*>(mask), flag, krig_idx,
        reinterpret_cast<vf4*>(out));
}

// Round 9
// 59.448 us; speedup vs baseline: 1.0827x; 1.0827x over previous
//
#include <hip/hip_runtime.h>

#define BSZ 512
#define NN  500
#define KK  100
#define SS  96
#define HIDN 32
#define ROWS (BSZ * NN)       // 256000 output rows
#define NF4  (ROWS * SS / 4)  // 6,144,000 float4 elements
#define F4PR (SS / 4)         // 24 float4 per row
#define NSLOT 8
#define FUSE_BLOCKS (NF4 / (256 * NSLOT))  // 3000, exact cover

typedef float vf4 __attribute__((ext_vector_type(4)));

// flag[row]: -1 -> copy x row; -2 -> zero row (gate=0); r>=0 -> kriged row r (gate=1)

// ------- kernel 1: prefix-sum (block 0) + flag clear to -1 (all blocks) -------
__global__ __launch_bounds__(512) void prep_kernel(const int* __restrict__ idx_of_node,
                                                   int* __restrict__ offs,
                                                   int4* __restrict__ flag4) {
    if (blockIdx.x == 0) {
        __shared__ int buf[BSZ];
        int t = threadIdx.x;
        int v = idx_of_node[t];
        buf[t] = v;
        __syncthreads();
        int acc = v;
        for (int d = 1; d < BSZ; d <<= 1) {
            int add = (t >= d) ? buf[t - d] : 0;
            __syncthreads();
            acc += add;
            buf[t] = acc;
            __syncthreads();
        }
        offs[t] = acc - v;  // exclusive prefix
    }
    int n4 = ROWS / 4;  // 64000 int4
    for (int i = blockIdx.x * 512 + threadIdx.x; i < n4; i += gridDim.x * 512)
        flag4[i] = make_int4(-1, -1, -1, -1);
}

// ---------------- kernel 2: gather -> MLP -> gate; write row descriptor ------------
__global__ __launch_bounds__(256) void gate_kernel(
    const float* __restrict__ y, const float* __restrict__ W1,
    const float* __restrict__ b1, const float* __restrict__ W2,
    const float* __restrict__ b2, const float* __restrict__ gumbel,
    const int* __restrict__ krig_idx, const int* __restrict__ offs,
    int* __restrict__ flag) {
    __shared__ float4 w1s[SS * HIDN / 4];  // 12 KB, row-major [s][j]
    __shared__ float b1s[HIDN];
    __shared__ float w2s[HIDN * 2];
    __shared__ float b2s[2];
    for (int i = threadIdx.x; i < SS * HIDN / 4; i += 256)
        w1s[i] = reinterpret_cast<const float4*>(W1)[i];
    if (threadIdx.x < HIDN) b1s[threadIdx.x] = b1[threadIdx.x];
    if (threadIdx.x < 2 * HIDN) w2s[threadIdx.x] = W2[threadIdx.x];
    if (threadIdx.x < 2) b2s[threadIdx.x] = b2[threadIdx.x];
    __syncthreads();

    int r = blockIdx.x * 256 + threadIdx.x;
    if (r >= BSZ * KK) return;
    int b = r / KK;
    int node = krig_idx[r];
    const float4* yrow = reinterpret_cast<const float4*>(y + (size_t)(b * NN + node) * SS);

    float h[HIDN];
#pragma unroll
    for (int j = 0; j < HIDN; ++j) h[j] = b1s[j];
#pragma unroll
    for (int s4 = 0; s4 < F4PR; ++s4) {
        float4 v = yrow[s4];
        float vv[4] = {v.x, v.y, v.z, v.w};
        const float4* wbase = &w1s[s4 * 4 * (HIDN / 4)];
#pragma unroll
        for (int q = 0; q < 4; ++q) {
#pragma unroll
            for (int j4 = 0; j4 < HIDN / 4; ++j4) {
                float4 w = wbase[q * (HIDN / 4) + j4];
                h[j4 * 4 + 0] += vv[q] * w.x;
                h[j4 * 4 + 1] += vv[q] * w.y;
                h[j4 * 4 + 2] += vv[q] * w.z;
                h[j4 * 4 + 3] += vv[q] * w.w;
            }
        }
    }
    float l0 = b2s[0], l1 = b2s[1];
#pragma unroll
    for (int j = 0; j < HIDN; ++j) {
        float hr = fmaxf(h[j], 0.0f);
        l0 += hr * w2s[j * 2 + 0];
        l1 += hr * w2s[j * 2 + 1];
    }
    float g0 = gumbel[r * 2 + 0], g1 = gumbel[r * 2 + 1];
    // straight-through hard gumbel: forward value is exactly one-hot {0,1}
    int on = (l1 + g1 > l0 + g0);
    flag[offs[b] + node] = on ? r : -2;  // gate==0 -> exact zero row
}

// ------- kernel 3: fused single-pass output; per-row tri-state descriptor ----------
// Best-known config (round-6 A/B): PLAIN loads (L3 serves ~half of x), NT stores
// (98 MB write-once stream must not evict the read set from L2/L3).
__global__ __launch_bounds__(256) void fuse_kernel(
    const vf4* __restrict__ x4, const vf4* __restrict__ y4,
    const vf4* __restrict__ mask4, const int* __restrict__ flag,
    const int* __restrict__ krig_idx, vf4* __restrict__ out4) {
    const int t0 = blockIdx.x * (256 * NSLOT) + threadIdx.x;  // 32 KB contiguous/block

    int fr[NSLOT];
#pragma unroll
    for (int k = 0; k < NSLOT; ++k) {
        int idx = t0 + k * 256;
        fr[k] = flag[idx / F4PR];
    }
    vf4 xv[NSLOT];
#pragma unroll
    for (int k = 0; k < NSLOT; ++k) {
        int idx = t0 + k * 256;
        int r = fr[k];
        vf4 v = (vf4)(0.0f);
        if (r == -1) {
            v = x4[idx];                           // ~80% of rows: straight copy
        } else if (r >= 0) {
            int row = idx / F4PR;
            int c = idx - row * F4PR;
            int b = r / KK;
            int node = krig_idx[r];                // 200 KB table, L2-hit
            vf4 m = mask4[r * F4PR + c];
            v = m * y4[(b * NN + node) * F4PR + c];  // gate==1 folded (exactly 1.0)
        }
        xv[k] = v;                                 // r==-2: exact zeros
    }
#pragma unroll
    for (int k = 0; k < NSLOT; ++k) {
        int idx = t0 + k * 256;
        __builtin_nontemporal_store(xv[k], out4 + idx);
    }
}

extern "C" void kernel_launch(void* const* d_in, const int* in_sizes, int n_in,
                              void* d_out, int out_size, void* d_ws, size_t ws_size,
                              hipStream_t stream) {
    const float* x      = (const float*)d_in[0];
    const float* y      = (const float*)d_in[1];
    const float* W1     = (const float*)d_in[2];
    const float* b1     = (const float*)d_in[3];
    const float* W2     = (const float*)d_in[4];
    const float* b2     = (const float*)d_in[5];
    const float* mask   = (const float*)d_in[6];
    const float* gumbel = (const float*)d_in[7];
    const int* krig_idx = (const int*)d_in[8];
    const int* idx_of_node = (const int*)d_in[9];
    float* out = (float*)d_out;

    int* offs = (int*)d_ws;                    // 512 ints
    int* flag = offs + BSZ;                    // 256000 ints (1 MB), 16B-aligned

    prep_kernel<<<128, 512, 0, stream>>>(idx_of_node, offs,
                                         reinterpret_cast<int4*>(flag));

    int rows = BSZ * KK;
    gate_kernel<<<(rows + 255) / 256, 256, 0, stream>>>(
        y, W1, b1, W2, b2, gumbel, krig_idx, offs, flag);

    fuse_kernel<<<FUSE_BLOCKS, 256, 0, stream>>>(
        reinterpret_cast<const vf4*>(x), reinterpret_cast<const vf4*>(y),
        reinterpret_cast<const vf4*>(mask), flag, krig_idx,
        reinterpret_cast<vf4*>(out));
}